// Round 15
// baseline (100.788 us; speedup 1.0000x reference)
//
#include <hip/hip_runtime.h>
#include <hip/hip_bf16.h>

#define NV 1024
#define NE 2048

typedef unsigned short u16;
typedef unsigned char u8;
typedef unsigned long long u64;
typedef __attribute__((ext_vector_type(8))) short bf16x8;
typedef __attribute__((ext_vector_type(4))) float f32x4;
typedef __attribute__((ext_vector_type(16))) float f32x16;
typedef __attribute__((ext_vector_type(2))) long i64x2;

__device__ __forceinline__ float bf2f(u16 u) { return __uint_as_float(((unsigned)u) << 16); }
__device__ __forceinline__ u16 f2bf(float f) {
  unsigned x = __float_as_uint(f);
  return (u16)((x + 0x7fffu + ((x >> 16) & 1u)) >> 16);
}
// float -> OCP e4m3fn, RNE, saturating, subnormal-continuous.
__device__ __forceinline__ u8 f2fp8(float f) {
  unsigned x = __float_as_uint(f);
  unsigned sgn = (x >> 24) & 0x80;
  float af = __uint_as_float(x & 0x7fffffff);
  unsigned q;
  if (af >= 448.f) {
    q = 0x7e;
  } else if (af < 0.015625f) {        // subnormal range, quantum 2^-9
    q = (unsigned)rintf(af * 512.f);  // 8 == first normal (2^-6): continuous
  } else {
    unsigned xa = x & 0x7fffffff;
    xa += 0x7ffff + ((xa >> 20) & 1);  // RNE into bit 20
    q = (xa >> 20) - 960;              // (exp127<<3 | man3) - (120<<3)
    if (q > 0x7e) q = 0x7e;
  }
  return (u8)(sgn | q);
}

// async global->LDS, 16B per lane, wave-uniform LDS base + lane*16
#define GLL(src, dst)                                                        \
  __builtin_amdgcn_global_load_lds(                                          \
      (const __attribute__((address_space(1))) void*)(src),                  \
      (__attribute__((address_space(3))) void*)(dst), 16, 0, 0)

template <int N>
__device__ __forceinline__ void waitcnt_vm() {
  if constexpr (N == 0) asm volatile("s_waitcnt vmcnt(0)" ::: "memory");
  else if constexpr (N == 3) asm volatile("s_waitcnt vmcnt(3)" ::: "memory");
  else if constexpr (N == 8) asm volatile("s_waitcnt vmcnt(8)" ::: "memory");
}
__device__ __forceinline__ void waitcnt_lgkm0() {
  asm volatile("s_waitcnt lgkmcnt(0)" ::: "memory");
}
__device__ __forceinline__ void barrier_raw() { __builtin_amdgcn_s_barrier(); }

// Swizzled LDS layout: logical byte L lives at physical P = L ^ (((L>>6)&7)<<4)
// (bijective). global_load_lds writes linear physical granules, so the
// per-lane GLOBAL SOURCE is permuted by the inverse map; reads apply fwdswz.
__device__ __forceinline__ void invswz(int g, int& row, int& kq) {
  int pb = g * 16;
  int lb = pb ^ ((((pb >> 8) & 1) << 6) | (((pb >> 7) & 1) << 5) |
                 ((((pb >> 6) ^ (pb >> 8)) & 1) << 4));
  row = lb >> 6;
  kq = lb & 63;
}
__device__ __forceinline__ int fwdswz(int la) { return la ^ (((la >> 6) & 7) << 4); }

// ---------------------------------------------------------------------------
// FP8 2-wave intra-block split-K bt-GEMM (steps 5 & 7): 128 threads, output
// tile 64x64, mfma_f32_32x32x16_fp8_fp8. LDS tile = [64 rows][64 K] fp8 = 4KB.
// Wave w pipelines K-half depth-2, counted vmcnt, no loop barriers.
// unsc multiplies the accumulator on store. Static acc indices (rule #20).
// EPI 0: f32 store of acc*unsc. EPI 1: bf16 store of acc*unsc*Gm[m][n].
// Requires K/128 even >= 2.
// ---------------------------------------------------------------------------
template <int EPI>
__global__ __launch_bounds__(128) void mfma8_w2(
    const u8* __restrict__ A, int lda, long sA,
    const u8* __restrict__ BT, int ldb, long sBT,
    void* __restrict__ Cp, int ldc, long sC, int K, float unsc,
    const float* __restrict__ Gm) {
  __shared__ __align__(16) char L[32768];
  const int t = threadIdx.x;
  const int wave = t >> 6, lane = t & 63;
  const int l31 = lane & 31, lh = lane >> 5;
  const int m0 = blockIdx.x * 64, n0 = blockIdx.y * 64;
  const int zz = blockIdx.z;
  const u8* Ab = A + sA * zz;
  const u8* Bb = BT + sBT * zz;

  char* Lw = L + wave * 16384;
  char* A0 = Lw;
  char* B0 = Lw + 4096;
  char* A1 = Lw + 8192;
  char* B1 = Lw + 12288;

  int rL[4], qL[4];
#pragma unroll
  for (int j = 0; j < 4; j++) invswz(j * 64 + lane, rL[j], qL[j]);

  f32x16 acc[2][2] = {};

  auto stage = [&](char* Ad, char* Bd, int tile) {
    waitcnt_lgkm0();
    const long kb = (long)tile * 64;
#pragma unroll
    for (int j = 0; j < 4; j++)
      GLL(Ab + (long)(m0 + rL[j]) * lda + kb + qL[j], Ad + j * 1024);
#pragma unroll
    for (int j = 0; j < 4; j++)
      GLL(Bb + (long)(n0 + rL[j]) * ldb + kb + qL[j], Bd + j * 1024);
  };
  auto comp = [&](const char* A_, const char* B_) {
#pragma unroll
    for (int kss2 = 0; kss2 < 2; kss2++) {
      i64x2 av[2], bv[2];
#pragma unroll
      for (int mi = 0; mi < 2; mi++)
        av[mi] = *(const i64x2*)(A_ + fwdswz((mi * 32 + l31) * 64 + kss2 * 32 + lh * 16));
#pragma unroll
      for (int ni = 0; ni < 2; ni++)
        bv[ni] = *(const i64x2*)(B_ + fwdswz((ni * 32 + l31) * 64 + kss2 * 32 + lh * 16));
#pragma unroll
      for (int mi = 0; mi < 2; mi++)
#pragma unroll
        for (int ni = 0; ni < 2; ni++) {
          acc[mi][ni] = __builtin_amdgcn_mfma_f32_32x32x16_fp8_fp8(
              av[mi][0], bv[ni][0], acc[mi][ni], 0, 0, 0);
          acc[mi][ni] = __builtin_amdgcn_mfma_f32_32x32x16_fp8_fp8(
              av[mi][1], bv[ni][1], acc[mi][ni], 0, 0, 0);
        }
    }
  };

  const int nt2 = K / 128;
  const int tb = wave * nt2;
  stage(A0, B0, tb);
  for (int i = 0; i + 2 < nt2; i += 2) {
    stage(A1, B1, tb + i + 1);
    waitcnt_vm<8>();
    comp(A0, B0);
    stage(A0, B0, tb + i + 2);
    waitcnt_vm<8>();
    comp(A1, B1);
  }
  stage(A1, B1, tb + nt2 - 1);
  waitcnt_vm<8>();
  comp(A0, B0);
  waitcnt_vm<0>();
  comp(A1, B1);

  waitcnt_lgkm0();
  float4* myD = (float4*)Lw;
  const float* otD = (const float*)(L + (wave ^ 1) * 16384);
  if (wave == 0) {
#pragma unroll
    for (int ni = 0; ni < 2; ni++)
#pragma unroll
      for (int r4 = 0; r4 < 4; r4++)
        myD[r4 * 128 + ni * 64 + lane] =
            make_float4(acc[1][ni][r4 * 4 + 0], acc[1][ni][r4 * 4 + 1],
                        acc[1][ni][r4 * 4 + 2], acc[1][ni][r4 * 4 + 3]);
  } else {
#pragma unroll
    for (int ni = 0; ni < 2; ni++)
#pragma unroll
      for (int r4 = 0; r4 < 4; r4++)
        myD[r4 * 128 + ni * 64 + lane] =
            make_float4(acc[0][ni][r4 * 4 + 0], acc[0][ni][r4 * 4 + 1],
                        acc[0][ni][r4 * 4 + 2], acc[0][ni][r4 * 4 + 3]);
  }
  __syncthreads();

  auto store_one = [&](int m, int n, float vv) {
    if constexpr (EPI == 0) {
      ((float*)Cp)[sC * zz + (long)m * ldc + n] = vv * unsc;
    } else {
      ((u16*)Cp)[sC * zz + (long)m * ldc + n] = f2bf(vv * unsc * Gm[(long)m * NV + n]);
    }
  };
  if (wave == 0) {
#pragma unroll
    for (int ni = 0; ni < 2; ni++)
#pragma unroll
      for (int r = 0; r < 16; r++) {
        float vv = acc[0][ni][r] + otD[((r >> 2) * 128 + ni * 64 + lane) * 4 + (r & 3)];
        int m = m0 + (r & 3) + 8 * (r >> 2) + 4 * lh;
        store_one(m, n0 + ni * 32 + l31, vv);
      }
  } else {
#pragma unroll
    for (int ni = 0; ni < 2; ni++)
#pragma unroll
      for (int r = 0; r < 16; r++) {
        float vv = acc[1][ni][r] + otD[((r >> 2) * 128 + ni * 64 + lane) * 4 + (r & 3)];
        int m = m0 + 32 + (r & 3) + 8 * (r >> 2) + 4 * lh;
        store_one(m, n0 + ni * 32 + l31, vv);
      }
  }
}

// ---------------------------------------------------------------------------
// 16x16-frag 4-wave bt-GEMM for step 8 split-K (r7 config, bf16).
// ---------------------------------------------------------------------------
__global__ __launch_bounds__(256) void mfma_bt8(
    const u16* __restrict__ A, const u16* __restrict__ BT,
    float* __restrict__ Cp) {
  constexpr int FM = 4, FN = 2;
  __shared__ __align__(16) char As0[8192];
  __shared__ __align__(16) char As1[8192];
  __shared__ __align__(16) char Bs0[4096];
  __shared__ __align__(16) char Bs1[4096];
  const int t = threadIdx.x;
  const int wave = t >> 6, lane = t & 63;
  const int lhi = lane >> 4, llo = lane & 15;
  const int wm = (wave >> 1) * 64, wn = (wave & 1) * 32;
  const int m0 = blockIdx.y * 128;
  const int zz = blockIdx.z >> 3, ks = blockIdx.z & 7;
  const char* Ab = (const char*)(A + (long)NV * NV * zz + ks * 128);
  const char* Bb = (const char*)(BT + (long)64 * NV * zz + ks * 128);
  const long lda2 = (long)NV * 2, ldb2 = (long)NV * 2;

  int rA0, qA0, rA1, qA1;
  invswz(t, rA0, qA0);
  invswz(t + 256, rA1, qA1);
  const int wofs = (t & 192) * 16;

  f32x4 acc[FM][FN] = {};

  auto stage = [&](char* Ad, char* Bd, int k0) {
    const long kb = (long)k0 * 2;
    GLL(Ab + (long)(m0 + rA0) * lda2 + kb + qA0, Ad + wofs);
    GLL(Ab + (long)(m0 + rA1) * lda2 + kb + qA1, Ad + 4096 + wofs);
    GLL(Bb + (long)rA0 * ldb2 + kb + qA0, Bd + wofs);
  };
  auto compute = [&](const char* A_, const char* B_) {
    bf16x8 af[FM], bfv[FN];
#pragma unroll
    for (int mi = 0; mi < FM; mi++)
      af[mi] = *(const bf16x8*)(A_ + fwdswz((wm + mi * 16 + llo) * 64 + lhi * 16));
#pragma unroll
    for (int ni = 0; ni < FN; ni++)
      bfv[ni] = *(const bf16x8*)(B_ + fwdswz((wn + ni * 16 + llo) * 64 + lhi * 16));
#pragma unroll
    for (int mi = 0; mi < FM; mi++)
#pragma unroll
      for (int ni = 0; ni < FN; ni++)
        acc[mi][ni] =
            __builtin_amdgcn_mfma_f32_16x16x32_bf16(af[mi], bfv[ni], acc[mi][ni], 0, 0, 0);
  };

  stage(As0, Bs0, 0);
  stage(As1, Bs1, 32);
  waitcnt_vm<3>();
  barrier_raw();
  compute(As0, Bs0);
  barrier_raw();
  stage(As0, Bs0, 64);
  waitcnt_vm<3>();
  barrier_raw();
  compute(As1, Bs1);
  barrier_raw();
  stage(As1, Bs1, 96);
  waitcnt_vm<3>();
  barrier_raw();
  compute(As0, Bs0);
  waitcnt_vm<0>();
  barrier_raw();
  compute(As1, Bs1);

#pragma unroll
  for (int mi = 0; mi < FM; mi++)
#pragma unroll
    for (int ni = 0; ni < FN; ni++)
#pragma unroll
      for (int r = 0; r < 4; r++) {
        int m = m0 + wm + mi * 16 + lhi * 4 + r;
        int n = wn + ni * 16 + llo;
        Cp[(long)ks * (NV * 256) + (long)m * 256 + zz * 64 + n] = acc[mi][ni][r];
      }
}

// ---------------------------------------------------------------------------
// f32 tiled matmul for step 1 only (Wh = h @ W). 64x64 tile, BK=16.
// ---------------------------------------------------------------------------
__global__ __launch_bounds__(256) void mm_f32(
    const float* __restrict__ Ap, const float* __restrict__ Bp,
    float* __restrict__ Cp) {
  __shared__ float As[16][68];
  __shared__ float Bs[16][68];
  const int t = threadIdx.x;
  const int tx = t & 15, ty = t >> 4;
  const int m0 = blockIdx.y * 64, n0 = blockIdx.x * 64;
  const int lr = t >> 2, lc4 = (t & 3) * 4;
  const int bk = t >> 4, bn = (t & 15) * 4;
  float acc[4][4] = {};
  for (int k0 = 0; k0 < 256; k0 += 16) {
    float4 a4 = *(const float4*)(Ap + (long)(m0 + lr) * 256 + k0 + lc4);
    As[lc4 + 0][lr] = a4.x;
    As[lc4 + 1][lr] = a4.y;
    As[lc4 + 2][lr] = a4.z;
    As[lc4 + 3][lr] = a4.w;
    float4 b4 = *(const float4*)(Bp + (long)(k0 + bk) * 256 + n0 + bn);
    Bs[bk][bn + 0] = b4.x;
    Bs[bk][bn + 1] = b4.y;
    Bs[bk][bn + 2] = b4.z;
    Bs[bk][bn + 3] = b4.w;
    __syncthreads();
#pragma unroll
    for (int kk = 0; kk < 16; kk++) {
      float a[4], b[4];
      *(float4*)a = *(const float4*)&As[kk][ty * 4];
      *(float4*)b = *(const float4*)&Bs[kk][tx * 4];
#pragma unroll
      for (int i = 0; i < 4; i++)
#pragma unroll
        for (int j = 0; j < 4; j++) acc[i][j] = fmaf(a[i], b[j], acc[i][j]);
    }
    __syncthreads();
  }
#pragma unroll
  for (int i = 0; i < 4; i++)
#pragma unroll
    for (int j = 0; j < 4; j++)
      Cp[(long)(m0 + ty * 4 + i) * 256 + n0 + tx * 4 + j] = acc[i][j];
}

// Build Mbf/Mtbf (fp8: 1.0 = 0x38) AND fused per-(e, v-tile) partial cnt/qe
// sums. part[(j*16+b)*NE + e], j=0 cnt, j=1..4 qe-sums.
__global__ __launch_bounds__(256) void k_conv(const int* __restrict__ inc,
                                              const float* __restrict__ qe,
                                              u8* __restrict__ Mbf,
                                              u8* __restrict__ Mtbf,
                                              float* __restrict__ part) {
  __shared__ u8 tile[64][68];
  const int e0 = blockIdx.x * 64, v0 = blockIdx.y * 64;
  const int t = threadIdx.x;
#pragma unroll
  for (int p = 0; p < 4; p++) {
    int r = p * 16 + (t >> 4);
    int c4 = (t & 15) * 4;
    int4 q = *(const int4*)(inc + (long)(v0 + r) * NE + e0 + c4);
    uchar4 w;
    w.x = q.x > 0 ? 0x38 : 0;
    w.y = q.y > 0 ? 0x38 : 0;
    w.z = q.z > 0 ? 0x38 : 0;
    w.w = q.w > 0 ? 0x38 : 0;
    *(uchar4*)&Mbf[(long)(v0 + r) * NE + e0 + c4] = w;
    tile[c4 + 0][r] = w.x;
    tile[c4 + 1][r] = w.y;
    tile[c4 + 2][r] = w.z;
    tile[c4 + 3][r] = w.w;
  }
  __syncthreads();
#pragma unroll
  for (int p = 0; p < 4; p++) {
    int er = p * 16 + (t >> 4);
    int vc4 = (t & 15) * 4;
    uchar4 w;
    w.x = tile[er][vc4 + 0];
    w.y = tile[er][vc4 + 1];
    w.z = tile[er][vc4 + 2];
    w.w = tile[er][vc4 + 3];
    *(uchar4*)&Mtbf[(long)(e0 + er) * NV + v0 + vc4] = w;
  }
  int er = t >> 2, q4 = t & 3;
  float c = 0, s0 = 0, s1 = 0, s2 = 0, s3 = 0;
  for (int vl = q4 * 16; vl < q4 * 16 + 16; vl++) {
    if (tile[er][vl]) {
      c += 1.f;
      const float* q4p = &qe[(long)(v0 + vl) * 4];
      s0 += q4p[0];
      s1 += q4p[1];
      s2 += q4p[2];
      s3 += q4p[3];
    }
  }
#pragma unroll
  for (int m = 1; m <= 2; m <<= 1) {
    c += __shfl_xor(c, m);
    s0 += __shfl_xor(s0, m);
    s1 += __shfl_xor(s1, m);
    s2 += __shfl_xor(s2, m);
    s3 += __shfl_xor(s3, m);
  }
  if (q4 == 0) {
    int b = blockIdx.y;
    int e = e0 + er;
    part[(0 * 16 + b) * NE + e] = c;
    part[(1 * 16 + b) * NE + e] = s0;
    part[(2 * 16 + b) * NE + e] = s1;
    part[(3 * 16 + b) * NE + e] = s2;
    part[(4 * 16 + b) * NE + e] = s3;
  }
}

// Whht[c][u] = bf16(Wh[u][c]) — transpose to [256][1024] bf16
__global__ __launch_bounds__(256) void k_trw(const float* __restrict__ Wh,
                                             u16* __restrict__ Whht) {
  __shared__ u16 tile[64][65];
  const int c0 = blockIdx.x * 64, v0 = blockIdx.y * 64;
  const int t = threadIdx.x;
#pragma unroll
  for (int p = 0; p < 4; p++) {
    int r = p * 16 + (t >> 4);
    int c4 = (t & 15) * 4;
    float4 q = *(const float4*)(Wh + (long)(v0 + r) * 256 + c0 + c4);
    tile[c4 + 0][r] = f2bf(q.x);
    tile[c4 + 1][r] = f2bf(q.y);
    tile[c4 + 2][r] = f2bf(q.z);
    tile[c4 + 3][r] = f2bf(q.w);
  }
  __syncthreads();
#pragma unroll
  for (int p = 0; p < 4; p++) {
    int cr = p * 16 + (t >> 4);
    int vc4 = (t & 15) * 4;
    ushort4 w;
    w.x = tile[cr][vc4 + 0];
    w.y = tile[cr][vc4 + 1];
    w.z = tile[cr][vc4 + 2];
    w.w = tile[cr][vc4 + 3];
    *(ushort4*)&Whht[(long)(c0 + cr) * NV + v0 + vc4] = w;
  }
}

// qv[v,h] = Whh[v,h,:].a_v ; qe[v,h] = Whh[v,h,:].a_e
__global__ __launch_bounds__(256) void k_qse1(const float* __restrict__ Wh,
                                              const float* __restrict__ attn_w,
                                              float* __restrict__ qv, float* __restrict__ qe) {
  int v = blockIdx.x, t = threadIdx.x;
  int d = t & 63, h = t >> 6;
  float x = Wh[(long)v * 256 + t];
  float pv = x * attn_w[d];
  float pe = x * attn_w[64 + d];
  for (int s = 32; s; s >>= 1) {
    pv += __shfl_down(pv, s);
    pe += __shfl_down(pe, s);
  }
  if (d == 0) {
    qv[v * 4 + h] = pv;
    qe[v * 4 + h] = pe;
  }
}

// Deterministic reduction of the 16 slabs. se holds RAW sums.
__global__ __launch_bounds__(256) void k_sered(const float* __restrict__ part,
                                               float* __restrict__ cnt, float* __restrict__ se) {
  int e = blockIdx.x * 256 + threadIdx.x;
  int j = blockIdx.y;
  float s = 0;
  for (int b = 0; b < 16; b++) s += part[(j * 16 + b) * NE + e];
  if (j == 0)
    cnt[e] = s;
  else
    se[e * 4 + (j - 1)] = s;
}

// Per (v,u): gate G via 2->32->1 MLP, and wce (fp8, x512) = ce.(enc_w @ a_c)
__global__ __launch_bounds__(256) void k_G(const float* __restrict__ ce,
                                           const float* __restrict__ enc_w,
                                           const float* __restrict__ attn_w,
                                           const float* __restrict__ g1w,
                                           const float* __restrict__ g1b,
                                           const float* __restrict__ g2w,
                                           const float* __restrict__ g2b,
                                           float* __restrict__ G, u8* __restrict__ wce) {
  long idx = (long)blockIdx.x * 256 + threadIdx.x;
  float2 c = *(const float2*)(ce + idx * 2);
  float ew0 = 0, ew1 = 0;
#pragma unroll
  for (int j = 0; j < 8; j++) {
    float ac = attn_w[128 + j];
    ew0 += enc_w[j] * ac;
    ew1 += enc_w[8 + j] * ac;
  }
  wce[idx] = f2fp8((c.x * ew0 + c.y * ew1) * 512.f);
  float s = g2b[0];
#pragma unroll
  for (int j = 0; j < 32; j++) {
    float zz = fmaxf(c.x * g1w[j] + c.y * g1w[32 + j] + g1b[j], 0.f);
    s = fmaf(zz, g2w[j], s);
  }
  G[idx] = 1.f / (1.f + expf(-s));
}

// Per v: scores -> leaky_relu -> mask -> softmax over E -> ap (fp8 planes,
// scaled x 2^17), s_v. Thread t owns e in [t*8, t*8+8): all global accesses
// are 8-16B/lane coalesced (u64 mask load from Mbf, float4 P/cnt/se loads,
// u64 ap stores) — fixes the 1B/lane scatter that made this kernel 42us.
__global__ __launch_bounds__(256) void k_softmax(
    const float* __restrict__ P, const u8* __restrict__ Mbf, const float* __restrict__ cnt,
    const float* __restrict__ qv, const float* __restrict__ se, const float* __restrict__ ce,
    const float* __restrict__ enc_w, const float* __restrict__ attn_w,
    const float* __restrict__ enc_b, u8* __restrict__ ap, float* __restrict__ sv) {
  int v = blockIdx.x, t = threadIdx.x;
  float ew0 = 0, ew1 = 0, ebac = 0;
#pragma unroll
  for (int j = 0; j < 8; j++) {
    float ac = attn_w[128 + j];
    ew0 += enc_w[j] * ac;
    ew1 += enc_w[8 + j] * ac;
    ebac += enc_b[j] * ac;
  }
  float dce = ce[((long)v * NV + v) * 2] * ew0 + ce[((long)v * NV + v) * 2 + 1] * ew1;
  float svh[4];
#pragma unroll
  for (int hh = 0; hh < 4; hh++) svh[hh] = qv[v * 4 + hh];

  const int e0 = t * 8;
  u64 mb = *(const u64*)(Mbf + (long)v * NE + e0);
  float pv8[8], cn8[8];
  *(float4*)&pv8[0] = *(const float4*)(P + (long)v * NE + e0);
  *(float4*)&pv8[4] = *(const float4*)(P + (long)v * NE + e0 + 4);
  *(float4*)&cn8[0] = *(const float4*)(cnt + e0);
  *(float4*)&cn8[4] = *(const float4*)(cnt + e0 + 4);
  float se8[8][4];
#pragma unroll
  for (int i = 0; i < 8; i++) *(float4*)&se8[i][0] = *(const float4*)(se + (long)(e0 + i) * 4);

  float sc[8][4];
  float invn[8], msk[8];
  float mx[4] = {-3e38f, -3e38f, -3e38f, -3e38f};
#pragma unroll
  for (int i = 0; i < 8; i++) {
    float cnte = cn8[i];
    float mask = ((mb >> (8 * i)) & 0xff) ? 1.f : 0.f;
    float nve = cnte - mask;
    float inv = nve > 0.f ? 1.f / nve : 0.f;
    float rdg = 1.f / fmaxf(cnte, 1.f);
    invn[i] = inv;
    msk[i] = mask;
    float cc = inv * (pv8[i] - mask * dce) + ebac;
#pragma unroll
    for (int hh = 0; hh < 4; hh++) {
      float s = svh[hh] + se8[i][hh] * rdg + cc;
      s = s > 0.f ? s : 0.2f * s;
      s = mask > 0.f ? s : -1e9f;
      sc[i][hh] = s;
      mx[hh] = fmaxf(mx[hh], s);
    }
  }
  __shared__ float red[4][256];
#pragma unroll
  for (int hh = 0; hh < 4; hh++) red[hh][t] = mx[hh];
  __syncthreads();
  for (int s = 128; s; s >>= 1) {
    if (t < s)
#pragma unroll
      for (int hh = 0; hh < 4; hh++) red[hh][t] = fmaxf(red[hh][t], red[hh][t + s]);
    __syncthreads();
  }
  float gm[4];
#pragma unroll
  for (int hh = 0; hh < 4; hh++) gm[hh] = red[hh][0];
  __syncthreads();

  float lsum[4] = {0, 0, 0, 0};
#pragma unroll
  for (int i = 0; i < 8; i++)
#pragma unroll
    for (int hh = 0; hh < 4; hh++) {
      float p = expf(sc[i][hh] - gm[hh]);
      sc[i][hh] = p;
      lsum[hh] += p;
    }
#pragma unroll
  for (int hh = 0; hh < 4; hh++) red[hh][t] = lsum[hh];
  __syncthreads();
  for (int s = 128; s; s >>= 1) {
    if (t < s)
#pragma unroll
      for (int hh = 0; hh < 4; hh++) red[hh][t] += red[hh][t + s];
    __syncthreads();
  }
  float inv_s[4];
#pragma unroll
  for (int hh = 0; hh < 4; hh++) inv_s[hh] = 1.f / red[hh][0];
  __syncthreads();

  float lsv[4] = {0, 0, 0, 0};
#pragma unroll
  for (int hh = 0; hh < 4; hh++) {
    u64 packed = 0;
#pragma unroll
    for (int i = 0; i < 8; i++) {
      float a = sc[i][hh] * inv_s[hh] * msk[i] * invn[i];
      packed |= (u64)f2fp8(a * 131072.f) << (8 * i);
      lsv[hh] += a;
    }
    *(u64*)(ap + (long)hh * NV * NE + (long)v * NE + e0) = packed;
  }
#pragma unroll
  for (int hh = 0; hh < 4; hh++) red[hh][t] = lsv[hh];
  __syncthreads();
  for (int s = 128; s; s >>= 1) {
    if (t < s)
#pragma unroll
      for (int hh = 0; hh < 4; hh++) red[hh][t] += red[hh][t + s];
    __syncthreads();
  }
  if (t == 0)
#pragma unroll
    for (int hh = 0; hh < 4; hh++) sv[v * 4 + hh] = red[hh][0];
}

// Fused: sum 8 split-K partials + residual + LayerNorm -> out
__global__ __launch_bounds__(256) void k_redln(
    const float* __restrict__ part, const float* __restrict__ Wh,
    const float* __restrict__ G, const float* __restrict__ sv,
    const float* __restrict__ lng, const float* __restrict__ lnb,
    float* __restrict__ out) {
  int v = blockIdx.x, t = threadIdx.x;
  float x = 0.f;
#pragma unroll
  for (int s = 0; s < 8; s++) x += part[(long)s * NV * 256 + (long)v * 256 + t];
  int z = t >> 6;
  float corr = 1.f - sv[v * 4 + z] * G[(long)v * NV + v];
  x += Wh[(long)v * 256 + t] * corr;
  __shared__ float red[256];
  red[t] = x;
  __syncthreads();
  for (int s = 128; s; s >>= 1) {
    if (t < s) red[t] += red[t + s];
    __syncthreads();
  }
  float mu = red[0] * (1.f / 256.f);
  __syncthreads();
  float d = x - mu;
  red[t] = d * d;
  __syncthreads();
  for (int s = 128; s; s >>= 1) {
    if (t < s) red[t] += red[t + s];
    __syncthreads();
  }
  float var = red[0] * (1.f / 256.f);
  out[(long)v * 256 + t] = d / sqrtf(var + 1e-5f) * lng[t] + lnb[t];
}

extern "C" void kernel_launch(void* const* d_in, const int* in_sizes, int n_in,
                              void* d_out, int out_size, void* d_ws, size_t ws_size,
                              hipStream_t stream) {
  const float* h = (const float*)d_in[0];
  const float* ce = (const float*)d_in[1];
  const float* W = (const float*)d_in[2];
  const float* attn_w = (const float*)d_in[3];
  const float* enc_w = (const float*)d_in[4];
  const float* enc_b = (const float*)d_in[5];
  const float* g1w = (const float*)d_in[6];
  const float* g1b = (const float*)d_in[7];
  const float* g2w = (const float*)d_in[8];
  const float* g2b = (const float*)d_in[9];
  const float* lng = (const float*)d_in[10];
  const float* lnb = (const float*)d_in[11];
  const int* inc = (const int*)d_in[12];
  float* out = (float*)d_out;

  size_t off = 0;
  char* base = (char*)d_ws;
  auto alloc = [&](size_t bytes) {
    void* p = base + off;
    off += (bytes + 255) & ~(size_t)255;
    return p;
  };
  float* Wh = (float*)alloc((size_t)NV * 256 * 4);
  float* cnt = (float*)alloc((size_t)NE * 4);
  float* qv = (float*)alloc((size_t)NV * 4 * 4);
  float* qe = (float*)alloc((size_t)NV * 4 * 4);
  float* se = (float*)alloc((size_t)NE * 4 * 4);
  float* sv = (float*)alloc((size_t)NV * 4 * 4);
  float* G = (float*)alloc((size_t)NV * NV * 4);
  u8* wce = (u8*)alloc((size_t)NV * NV);
  u8* Mbf = (u8*)alloc((size_t)NV * NE);
  u16* Whht = (u16*)alloc((size_t)256 * NV * 2);
  float* P = (float*)alloc((size_t)NV * NE * 4);  // also: split-K partials (8MB)
  u8* ap = (u8*)alloc((size_t)4 * NV * NE);
  u16* Bh = (u16*)alloc((size_t)4 * NV * NV * 2);
  // aliases (lifetimes don't overlap):
  float* part = P;          // cnt/qe partials (640KB), dead before P written
  u8* Mtbf = (u8*)Bh;       // Mtbf (2MB) dead before Bh written (step 7)
  float* part8 = P;         // step-8 split-K partials, P dead after k_softmax
  (void)ws_size;
  (void)in_sizes;
  (void)n_in;
  (void)out_size;

  // 1. Wh = h @ W (f32)
  mm_f32<<<dim3(256 / 64, NV / 64), 256, 0, stream>>>(h, W, Wh);
  // 1b. Whht = Wh^T bf16
  k_trw<<<dim3(256 / 64, NV / 64), 256, 0, stream>>>(Wh, Whht);
  // 2. qv, qe
  k_qse1<<<NV, 256, 0, stream>>>(Wh, attn_w, qv, qe);
  // 3. fp8 incidence + fused cnt/qe partial sums (needs qe)
  k_conv<<<dim3(NE / 64, NV / 64), 256, 0, stream>>>(inc, qe, Mbf, Mtbf, part);
  k_sered<<<dim3(NE / 256, 5), 256, 0, stream>>>(part, cnt, se);
  // 4. G, wce(fp8 x512)
  k_G<<<(NV * NV) / 256, 256, 0, stream>>>(ce, enc_w, attn_w, g1w, g1b, g2w, g2b, G, wce);
  // 5. P = wce @ M (M=1024, N=2048, K=1024) in fp8; unscale 1/512.
  mfma8_w2<0><<<dim3(NV / 64, NE / 64, 1), 128, 0, stream>>>(
      wce, NV, 0, Mtbf, NV, 0, P, NE, 0, NV, 1.f / 512.f, nullptr);
  // 6. softmax -> ap planes (fp8 x 2^17), s_v. Coalesced e-contiguous layout.
  k_softmax<<<NV, 256, 0, stream>>>(P, Mbf, cnt, qv, se, ce, enc_w, attn_w, enc_b, ap, sv);
  // 7. Bh = (ap_h @ M^T) * G (4 x M=N=1024, K=2048) in fp8; unscale 2^-17.
  mfma8_w2<1><<<dim3(NV / 64, NV / 64, 4), 128, 0, stream>>>(
      ap, NE, (long)NV * NE, Mbf, NE, 0, Bh, NV, (long)NV * NV, NE, 1.f / 131072.f, G);
  // 8. split-K=8 partials via 4-wave mfma_bt8 (bf16, r7 config).
  mfma_bt8<<<dim3(1, NV / 128, 32), 256, 0, stream>>>(Bh, Whht, part8);
  // 9. reduce partials + residual + LayerNorm
  k_redln<<<NV, 256, 0, stream>>>(part8, Wh, G, sv, lng, lnb, out);
}

// Round 16
// 93.770 us; speedup vs baseline: 1.0748x; 1.0748x over previous
//
#include <hip/hip_runtime.h>
#include <hip/hip_bf16.h>

#define NV 1024
#define NE 2048

typedef unsigned short u16;
typedef unsigned char u8;
typedef unsigned long long u64;
typedef __attribute__((ext_vector_type(8))) short bf16x8;
typedef __attribute__((ext_vector_type(4))) float f32x4;
typedef __attribute__((ext_vector_type(16))) float f32x16;
typedef __attribute__((ext_vector_type(2))) long i64x2;

__device__ __forceinline__ float bf2f(u16 u) { return __uint_as_float(((unsigned)u) << 16); }
__device__ __forceinline__ u16 f2bf(float f) {
  unsigned x = __float_as_uint(f);
  return (u16)((x + 0x7fffu + ((x >> 16) & 1u)) >> 16);
}
// float -> OCP e4m3fn, RNE, saturating, subnormal-continuous.
__device__ __forceinline__ u8 f2fp8(float f) {
  unsigned x = __float_as_uint(f);
  unsigned sgn = (x >> 24) & 0x80;
  float af = __uint_as_float(x & 0x7fffffff);
  unsigned q;
  if (af >= 448.f) {
    q = 0x7e;
  } else if (af < 0.015625f) {        // subnormal range, quantum 2^-9
    q = (unsigned)rintf(af * 512.f);  // 8 == first normal (2^-6): continuous
  } else {
    unsigned xa = x & 0x7fffffff;
    xa += 0x7ffff + ((xa >> 20) & 1);  // RNE into bit 20
    q = (xa >> 20) - 960;              // (exp127<<3 | man3) - (120<<3)
    if (q > 0x7e) q = 0x7e;
  }
  return (u8)(sgn | q);
}

// async global->LDS, 16B per lane, wave-uniform LDS base + lane*16
#define GLL(src, dst)                                                        \
  __builtin_amdgcn_global_load_lds(                                          \
      (const __attribute__((address_space(1))) void*)(src),                  \
      (__attribute__((address_space(3))) void*)(dst), 16, 0, 0)

template <int N>
__device__ __forceinline__ void waitcnt_vm() {
  if constexpr (N == 0) asm volatile("s_waitcnt vmcnt(0)" ::: "memory");
  else if constexpr (N == 3) asm volatile("s_waitcnt vmcnt(3)" ::: "memory");
  else if constexpr (N == 8) asm volatile("s_waitcnt vmcnt(8)" ::: "memory");
}
__device__ __forceinline__ void waitcnt_lgkm0() {
  asm volatile("s_waitcnt lgkmcnt(0)" ::: "memory");
}
__device__ __forceinline__ void barrier_raw() { __builtin_amdgcn_s_barrier(); }

// Swizzled LDS layout: logical byte L lives at physical P = L ^ (((L>>6)&7)<<4)
// (bijective). global_load_lds writes linear physical granules, so the
// per-lane GLOBAL SOURCE is permuted by the inverse map; reads apply fwdswz.
__device__ __forceinline__ void invswz(int g, int& row, int& kq) {
  int pb = g * 16;
  int lb = pb ^ ((((pb >> 8) & 1) << 6) | (((pb >> 7) & 1) << 5) |
                 ((((pb >> 6) ^ (pb >> 8)) & 1) << 4));
  row = lb >> 6;
  kq = lb & 63;
}
__device__ __forceinline__ int fwdswz(int la) { return la ^ (((la >> 6) & 7) << 4); }

// ---------------------------------------------------------------------------
// FP8 2-wave intra-block split-K bt-GEMM (steps 5 & 7): 128 threads, output
// tile 64x64, mfma_f32_32x32x16_fp8_fp8. LDS tile = [64 rows][64 K] fp8 = 4KB.
// Wave w pipelines K-half depth-2, counted vmcnt, no loop barriers.
// unsc multiplies the accumulator on store. Static acc indices (rule #20).
// EPI 0: bf16 store of acc*unsc (P). EPI 1: bf16 store of acc*unsc*Gm (Bh).
// Requires K/128 even >= 2.
// ---------------------------------------------------------------------------
template <int EPI>
__global__ __launch_bounds__(128) void mfma8_w2(
    const u8* __restrict__ A, int lda, long sA,
    const u8* __restrict__ BT, int ldb, long sBT,
    void* __restrict__ Cp, int ldc, long sC, int K, float unsc,
    const float* __restrict__ Gm) {
  __shared__ __align__(16) char L[32768];
  const int t = threadIdx.x;
  const int wave = t >> 6, lane = t & 63;
  const int l31 = lane & 31, lh = lane >> 5;
  const int m0 = blockIdx.x * 64, n0 = blockIdx.y * 64;
  const int zz = blockIdx.z;
  const u8* Ab = A + sA * zz;
  const u8* Bb = BT + sBT * zz;

  char* Lw = L + wave * 16384;
  char* A0 = Lw;
  char* B0 = Lw + 4096;
  char* A1 = Lw + 8192;
  char* B1 = Lw + 12288;

  int rL[4], qL[4];
#pragma unroll
  for (int j = 0; j < 4; j++) invswz(j * 64 + lane, rL[j], qL[j]);

  f32x16 acc[2][2] = {};

  auto stage = [&](char* Ad, char* Bd, int tile) {
    waitcnt_lgkm0();
    const long kb = (long)tile * 64;
#pragma unroll
    for (int j = 0; j < 4; j++)
      GLL(Ab + (long)(m0 + rL[j]) * lda + kb + qL[j], Ad + j * 1024);
#pragma unroll
    for (int j = 0; j < 4; j++)
      GLL(Bb + (long)(n0 + rL[j]) * ldb + kb + qL[j], Bd + j * 1024);
  };
  auto comp = [&](const char* A_, const char* B_) {
#pragma unroll
    for (int kss2 = 0; kss2 < 2; kss2++) {
      i64x2 av[2], bv[2];
#pragma unroll
      for (int mi = 0; mi < 2; mi++)
        av[mi] = *(const i64x2*)(A_ + fwdswz((mi * 32 + l31) * 64 + kss2 * 32 + lh * 16));
#pragma unroll
      for (int ni = 0; ni < 2; ni++)
        bv[ni] = *(const i64x2*)(B_ + fwdswz((ni * 32 + l31) * 64 + kss2 * 32 + lh * 16));
#pragma unroll
      for (int mi = 0; mi < 2; mi++)
#pragma unroll
        for (int ni = 0; ni < 2; ni++) {
          acc[mi][ni] = __builtin_amdgcn_mfma_f32_32x32x16_fp8_fp8(
              av[mi][0], bv[ni][0], acc[mi][ni], 0, 0, 0);
          acc[mi][ni] = __builtin_amdgcn_mfma_f32_32x32x16_fp8_fp8(
              av[mi][1], bv[ni][1], acc[mi][ni], 0, 0, 0);
        }
    }
  };

  const int nt2 = K / 128;
  const int tb = wave * nt2;
  stage(A0, B0, tb);
  for (int i = 0; i + 2 < nt2; i += 2) {
    stage(A1, B1, tb + i + 1);
    waitcnt_vm<8>();
    comp(A0, B0);
    stage(A0, B0, tb + i + 2);
    waitcnt_vm<8>();
    comp(A1, B1);
  }
  stage(A1, B1, tb + nt2 - 1);
  waitcnt_vm<8>();
  comp(A0, B0);
  waitcnt_vm<0>();
  comp(A1, B1);

  waitcnt_lgkm0();
  float4* myD = (float4*)Lw;
  const float* otD = (const float*)(L + (wave ^ 1) * 16384);
  if (wave == 0) {
#pragma unroll
    for (int ni = 0; ni < 2; ni++)
#pragma unroll
      for (int r4 = 0; r4 < 4; r4++)
        myD[r4 * 128 + ni * 64 + lane] =
            make_float4(acc[1][ni][r4 * 4 + 0], acc[1][ni][r4 * 4 + 1],
                        acc[1][ni][r4 * 4 + 2], acc[1][ni][r4 * 4 + 3]);
  } else {
#pragma unroll
    for (int ni = 0; ni < 2; ni++)
#pragma unroll
      for (int r4 = 0; r4 < 4; r4++)
        myD[r4 * 128 + ni * 64 + lane] =
            make_float4(acc[0][ni][r4 * 4 + 0], acc[0][ni][r4 * 4 + 1],
                        acc[0][ni][r4 * 4 + 2], acc[0][ni][r4 * 4 + 3]);
  }
  __syncthreads();

  auto store_one = [&](int m, int n, float vv) {
    if constexpr (EPI == 0) {
      ((u16*)Cp)[sC * zz + (long)m * ldc + n] = f2bf(vv * unsc);
    } else {
      ((u16*)Cp)[sC * zz + (long)m * ldc + n] = f2bf(vv * unsc * Gm[(long)m * NV + n]);
    }
  };
  if (wave == 0) {
#pragma unroll
    for (int ni = 0; ni < 2; ni++)
#pragma unroll
      for (int r = 0; r < 16; r++) {
        float vv = acc[0][ni][r] + otD[((r >> 2) * 128 + ni * 64 + lane) * 4 + (r & 3)];
        int m = m0 + (r & 3) + 8 * (r >> 2) + 4 * lh;
        store_one(m, n0 + ni * 32 + l31, vv);
      }
  } else {
#pragma unroll
    for (int ni = 0; ni < 2; ni++)
#pragma unroll
      for (int r = 0; r < 16; r++) {
        float vv = acc[1][ni][r] + otD[((r >> 2) * 128 + ni * 64 + lane) * 4 + (r & 3)];
        int m = m0 + 32 + (r & 3) + 8 * (r >> 2) + 4 * lh;
        store_one(m, n0 + ni * 32 + l31, vv);
      }
  }
}

// ---------------------------------------------------------------------------
// 16x16-frag 4-wave bt-GEMM for step 8 split-K (r7 config, bf16).
// ---------------------------------------------------------------------------
__global__ __launch_bounds__(256) void mfma_bt8(
    const u16* __restrict__ A, const u16* __restrict__ BT,
    float* __restrict__ Cp) {
  constexpr int FM = 4, FN = 2;
  __shared__ __align__(16) char As0[8192];
  __shared__ __align__(16) char As1[8192];
  __shared__ __align__(16) char Bs0[4096];
  __shared__ __align__(16) char Bs1[4096];
  const int t = threadIdx.x;
  const int wave = t >> 6, lane = t & 63;
  const int lhi = lane >> 4, llo = lane & 15;
  const int wm = (wave >> 1) * 64, wn = (wave & 1) * 32;
  const int m0 = blockIdx.y * 128;
  const int zz = blockIdx.z >> 3, ks = blockIdx.z & 7;
  const char* Ab = (const char*)(A + (long)NV * NV * zz + ks * 128);
  const char* Bb = (const char*)(BT + (long)64 * NV * zz + ks * 128);
  const long lda2 = (long)NV * 2, ldb2 = (long)NV * 2;

  int rA0, qA0, rA1, qA1;
  invswz(t, rA0, qA0);
  invswz(t + 256, rA1, qA1);
  const int wofs = (t & 192) * 16;

  f32x4 acc[FM][FN] = {};

  auto stage = [&](char* Ad, char* Bd, int k0) {
    const long kb = (long)k0 * 2;
    GLL(Ab + (long)(m0 + rA0) * lda2 + kb + qA0, Ad + wofs);
    GLL(Ab + (long)(m0 + rA1) * lda2 + kb + qA1, Ad + 4096 + wofs);
    GLL(Bb + (long)rA0 * ldb2 + kb + qA0, Bd + wofs);
  };
  auto compute = [&](const char* A_, const char* B_) {
    bf16x8 af[FM], bfv[FN];
#pragma unroll
    for (int mi = 0; mi < FM; mi++)
      af[mi] = *(const bf16x8*)(A_ + fwdswz((wm + mi * 16 + llo) * 64 + lhi * 16));
#pragma unroll
    for (int ni = 0; ni < FN; ni++)
      bfv[ni] = *(const bf16x8*)(B_ + fwdswz((wn + ni * 16 + llo) * 64 + lhi * 16));
#pragma unroll
    for (int mi = 0; mi < FM; mi++)
#pragma unroll
      for (int ni = 0; ni < FN; ni++)
        acc[mi][ni] =
            __builtin_amdgcn_mfma_f32_16x16x32_bf16(af[mi], bfv[ni], acc[mi][ni], 0, 0, 0);
  };

  stage(As0, Bs0, 0);
  stage(As1, Bs1, 32);
  waitcnt_vm<3>();
  barrier_raw();
  compute(As0, Bs0);
  barrier_raw();
  stage(As0, Bs0, 64);
  waitcnt_vm<3>();
  barrier_raw();
  compute(As1, Bs1);
  barrier_raw();
  stage(As1, Bs1, 96);
  waitcnt_vm<3>();
  barrier_raw();
  compute(As0, Bs0);
  waitcnt_vm<0>();
  barrier_raw();
  compute(As1, Bs1);

#pragma unroll
  for (int mi = 0; mi < FM; mi++)
#pragma unroll
    for (int ni = 0; ni < FN; ni++)
#pragma unroll
      for (int r = 0; r < 4; r++) {
        int m = m0 + wm + mi * 16 + lhi * 4 + r;
        int n = wn + ni * 16 + llo;
        Cp[(long)ks * (NV * 256) + (long)m * 256 + zz * 64 + n] = acc[mi][ni][r];
      }
}

// ---------------------------------------------------------------------------
// Step 1: Wh = h @ W (f32 64x64 tile, BK=16) + FUSED transposed-bf16 epilogue
// writing Whht[c][u] (replaces the separate k_trw kernel).
// ---------------------------------------------------------------------------
__global__ __launch_bounds__(256) void mm_f32(
    const float* __restrict__ Ap, const float* __restrict__ Bp,
    float* __restrict__ Cp, u16* __restrict__ Whht) {
  __shared__ float As[16][68];
  __shared__ float Bs[16][68];
  __shared__ u16 ttile[64][68];
  const int t = threadIdx.x;
  const int tx = t & 15, ty = t >> 4;
  const int m0 = blockIdx.y * 64, n0 = blockIdx.x * 64;
  const int lr = t >> 2, lc4 = (t & 3) * 4;
  const int bk = t >> 4, bn = (t & 15) * 4;
  float acc[4][4] = {};
  for (int k0 = 0; k0 < 256; k0 += 16) {
    float4 a4 = *(const float4*)(Ap + (long)(m0 + lr) * 256 + k0 + lc4);
    As[lc4 + 0][lr] = a4.x;
    As[lc4 + 1][lr] = a4.y;
    As[lc4 + 2][lr] = a4.z;
    As[lc4 + 3][lr] = a4.w;
    float4 b4 = *(const float4*)(Bp + (long)(k0 + bk) * 256 + n0 + bn);
    Bs[bk][bn + 0] = b4.x;
    Bs[bk][bn + 1] = b4.y;
    Bs[bk][bn + 2] = b4.z;
    Bs[bk][bn + 3] = b4.w;
    __syncthreads();
#pragma unroll
    for (int kk = 0; kk < 16; kk++) {
      float a[4], b[4];
      *(float4*)a = *(const float4*)&As[kk][ty * 4];
      *(float4*)b = *(const float4*)&Bs[kk][tx * 4];
#pragma unroll
      for (int i = 0; i < 4; i++)
#pragma unroll
        for (int j = 0; j < 4; j++) acc[i][j] = fmaf(a[i], b[j], acc[i][j]);
    }
    __syncthreads();
  }
#pragma unroll
  for (int i = 0; i < 4; i++)
#pragma unroll
    for (int j = 0; j < 4; j++) {
      Cp[(long)(m0 + ty * 4 + i) * 256 + n0 + tx * 4 + j] = acc[i][j];
      ttile[tx * 4 + j][ty * 4 + i] = f2bf(acc[i][j]);  // [c_local][v_local]
    }
  __syncthreads();
  // coalesced transposed store: 4 threads per c-row, 16 u16 each
  const int cr = t >> 2, vc = (t & 3) * 16;
#pragma unroll
  for (int q = 0; q < 4; q++) {
    ushort4 w = *(const ushort4*)&ttile[cr][vc + q * 4];
    *(ushort4*)&Whht[(long)(n0 + cr) * NV + m0 + vc + q * 4] = w;
  }
}

// Build Mbf/Mtbf (fp8: 1.0 = 0x38) AND fused per-(e, v-tile) partial cnt/qe
// sums. part[(j*16+b)*NE + e], j=0 cnt, j=1..4 qe-sums.
__global__ __launch_bounds__(256) void k_conv(const int* __restrict__ inc,
                                              const float* __restrict__ qe,
                                              u8* __restrict__ Mbf,
                                              u8* __restrict__ Mtbf,
                                              float* __restrict__ part) {
  __shared__ u8 tile[64][68];
  const int e0 = blockIdx.x * 64, v0 = blockIdx.y * 64;
  const int t = threadIdx.x;
#pragma unroll
  for (int p = 0; p < 4; p++) {
    int r = p * 16 + (t >> 4);
    int c4 = (t & 15) * 4;
    int4 q = *(const int4*)(inc + (long)(v0 + r) * NE + e0 + c4);
    uchar4 w;
    w.x = q.x > 0 ? 0x38 : 0;
    w.y = q.y > 0 ? 0x38 : 0;
    w.z = q.z > 0 ? 0x38 : 0;
    w.w = q.w > 0 ? 0x38 : 0;
    *(uchar4*)&Mbf[(long)(v0 + r) * NE + e0 + c4] = w;
    tile[c4 + 0][r] = w.x;
    tile[c4 + 1][r] = w.y;
    tile[c4 + 2][r] = w.z;
    tile[c4 + 3][r] = w.w;
  }
  __syncthreads();
#pragma unroll
  for (int p = 0; p < 4; p++) {
    int er = p * 16 + (t >> 4);
    int vc4 = (t & 15) * 4;
    uchar4 w;
    w.x = tile[er][vc4 + 0];
    w.y = tile[er][vc4 + 1];
    w.z = tile[er][vc4 + 2];
    w.w = tile[er][vc4 + 3];
    *(uchar4*)&Mtbf[(long)(e0 + er) * NV + v0 + vc4] = w;
  }
  int er = t >> 2, q4 = t & 3;
  float c = 0, s0 = 0, s1 = 0, s2 = 0, s3 = 0;
  for (int vl = q4 * 16; vl < q4 * 16 + 16; vl++) {
    if (tile[er][vl]) {
      c += 1.f;
      const float* q4p = &qe[(long)(v0 + vl) * 4];
      s0 += q4p[0];
      s1 += q4p[1];
      s2 += q4p[2];
      s3 += q4p[3];
    }
  }
#pragma unroll
  for (int m = 1; m <= 2; m <<= 1) {
    c += __shfl_xor(c, m);
    s0 += __shfl_xor(s0, m);
    s1 += __shfl_xor(s1, m);
    s2 += __shfl_xor(s2, m);
    s3 += __shfl_xor(s3, m);
  }
  if (q4 == 0) {
    int b = blockIdx.y;
    int e = e0 + er;
    part[(0 * 16 + b) * NE + e] = c;
    part[(1 * 16 + b) * NE + e] = s0;
    part[(2 * 16 + b) * NE + e] = s1;
    part[(3 * 16 + b) * NE + e] = s2;
    part[(4 * 16 + b) * NE + e] = s3;
  }
}

// qv[v,h] = Whh[v,h,:].a_v ; qe[v,h] = Whh[v,h,:].a_e
__global__ __launch_bounds__(256) void k_qse1(const float* __restrict__ Wh,
                                              const float* __restrict__ attn_w,
                                              float* __restrict__ qv, float* __restrict__ qe) {
  int v = blockIdx.x, t = threadIdx.x;
  int d = t & 63, h = t >> 6;
  float x = Wh[(long)v * 256 + t];
  float pv = x * attn_w[d];
  float pe = x * attn_w[64 + d];
  for (int s = 32; s; s >>= 1) {
    pv += __shfl_down(pv, s);
    pe += __shfl_down(pe, s);
  }
  if (d == 0) {
    qv[v * 4 + h] = pv;
    qe[v * 4 + h] = pe;
  }
}

// Deterministic reduction of the 16 slabs. se holds RAW sums.
__global__ __launch_bounds__(256) void k_sered(const float* __restrict__ part,
                                               float* __restrict__ cnt, float* __restrict__ se) {
  int e = blockIdx.x * 256 + threadIdx.x;
  int j = blockIdx.y;
  float s = 0;
  for (int b = 0; b < 16; b++) s += part[(j * 16 + b) * NE + e];
  if (j == 0)
    cnt[e] = s;
  else
    se[e * 4 + (j - 1)] = s;
}

// Per (v,u): gate G via 2->32->1 MLP, and wce (fp8, x512) = ce.(enc_w @ a_c)
__global__ __launch_bounds__(256) void k_G(const float* __restrict__ ce,
                                           const float* __restrict__ enc_w,
                                           const float* __restrict__ attn_w,
                                           const float* __restrict__ g1w,
                                           const float* __restrict__ g1b,
                                           const float* __restrict__ g2w,
                                           const float* __restrict__ g2b,
                                           float* __restrict__ G, u8* __restrict__ wce) {
  long idx = (long)blockIdx.x * 256 + threadIdx.x;
  float2 c = *(const float2*)(ce + idx * 2);
  float ew0 = 0, ew1 = 0;
#pragma unroll
  for (int j = 0; j < 8; j++) {
    float ac = attn_w[128 + j];
    ew0 += enc_w[j] * ac;
    ew1 += enc_w[8 + j] * ac;
  }
  wce[idx] = f2fp8((c.x * ew0 + c.y * ew1) * 512.f);
  float s = g2b[0];
#pragma unroll
  for (int j = 0; j < 32; j++) {
    float zz = fmaxf(c.x * g1w[j] + c.y * g1w[32 + j] + g1b[j], 0.f);
    s = fmaf(zz, g2w[j], s);
  }
  G[idx] = 1.f / (1.f + __expf(-s));
}

// Per v: scores -> leaky_relu -> mask -> softmax over E -> ap (fp8 planes,
// scaled x 2^17), s_v. Thread t owns e in [t*8, t*8+8): coalesced u64/float4
// loads, u64 ap stores. Reductions: wave __shfl_xor + 4-slot LDS (3 barriers).
__global__ __launch_bounds__(256) void k_softmax(
    const u16* __restrict__ P, const u8* __restrict__ Mbf, const float* __restrict__ cnt,
    const float* __restrict__ qv, const float* __restrict__ se, const float* __restrict__ ce,
    const float* __restrict__ enc_w, const float* __restrict__ attn_w,
    const float* __restrict__ enc_b, u8* __restrict__ ap, float* __restrict__ sv) {
  int v = blockIdx.x, t = threadIdx.x;
  const int wave = t >> 6, lane = t & 63;
  float ew0 = 0, ew1 = 0, ebac = 0;
#pragma unroll
  for (int j = 0; j < 8; j++) {
    float ac = attn_w[128 + j];
    ew0 += enc_w[j] * ac;
    ew1 += enc_w[8 + j] * ac;
    ebac += enc_b[j] * ac;
  }
  float dce = ce[((long)v * NV + v) * 2] * ew0 + ce[((long)v * NV + v) * 2 + 1] * ew1;
  float svh[4];
#pragma unroll
  for (int hh = 0; hh < 4; hh++) svh[hh] = qv[v * 4 + hh];

  const int e0 = t * 8;
  u64 mb = *(const u64*)(Mbf + (long)v * NE + e0);
  ushort4 pb0 = *(const ushort4*)(P + (long)v * NE + e0);
  ushort4 pb1 = *(const ushort4*)(P + (long)v * NE + e0 + 4);
  float pv8[8], cn8[8];
  pv8[0] = bf2f(pb0.x); pv8[1] = bf2f(pb0.y); pv8[2] = bf2f(pb0.z); pv8[3] = bf2f(pb0.w);
  pv8[4] = bf2f(pb1.x); pv8[5] = bf2f(pb1.y); pv8[6] = bf2f(pb1.z); pv8[7] = bf2f(pb1.w);
  *(float4*)&cn8[0] = *(const float4*)(cnt + e0);
  *(float4*)&cn8[4] = *(const float4*)(cnt + e0 + 4);
  float se8[8][4];
#pragma unroll
  for (int i = 0; i < 8; i++) *(float4*)&se8[i][0] = *(const float4*)(se + (long)(e0 + i) * 4);

  float sc[8][4];
  float invn[8], msk[8];
  float mx[4] = {-3e38f, -3e38f, -3e38f, -3e38f};
#pragma unroll
  for (int i = 0; i < 8; i++) {
    float cnte = cn8[i];
    float mask = ((mb >> (8 * i)) & 0xff) ? 1.f : 0.f;
    float nve = cnte - mask;
    float inv = nve > 0.f ? 1.f / nve : 0.f;
    float rdg = 1.f / fmaxf(cnte, 1.f);
    invn[i] = inv;
    msk[i] = mask;
    float cc = inv * (pv8[i] - mask * dce) + ebac;
#pragma unroll
    for (int hh = 0; hh < 4; hh++) {
      float s = svh[hh] + se8[i][hh] * rdg + cc;
      s = s > 0.f ? s : 0.2f * s;
      s = mask > 0.f ? s : -1e9f;
      sc[i][hh] = s;
      mx[hh] = fmaxf(mx[hh], s);
    }
  }
  __shared__ float redM[4][4], redS[4][4], redV[4][4];  // [hh][wave]
#pragma unroll
  for (int hh = 0; hh < 4; hh++) {
    float x = mx[hh];
#pragma unroll
    for (int m = 1; m <= 32; m <<= 1) x = fmaxf(x, __shfl_xor(x, m));
    if (lane == 0) redM[hh][wave] = x;
  }
  __syncthreads();
  float gm[4];
#pragma unroll
  for (int hh = 0; hh < 4; hh++)
    gm[hh] = fmaxf(fmaxf(redM[hh][0], redM[hh][1]), fmaxf(redM[hh][2], redM[hh][3]));

  float lsum[4] = {0, 0, 0, 0};
#pragma unroll
  for (int i = 0; i < 8; i++)
#pragma unroll
    for (int hh = 0; hh < 4; hh++) {
      float p = __expf(sc[i][hh] - gm[hh]);
      sc[i][hh] = p;
      lsum[hh] += p;
    }
#pragma unroll
  for (int hh = 0; hh < 4; hh++) {
    float x = lsum[hh];
#pragma unroll
    for (int m = 1; m <= 32; m <<= 1) x += __shfl_xor(x, m);
    if (lane == 0) redS[hh][wave] = x;
  }
  __syncthreads();
  float inv_s[4];
#pragma unroll
  for (int hh = 0; hh < 4; hh++)
    inv_s[hh] = 1.f / (redS[hh][0] + redS[hh][1] + redS[hh][2] + redS[hh][3]);

  float lsv[4] = {0, 0, 0, 0};
#pragma unroll
  for (int hh = 0; hh < 4; hh++) {
    u64 packed = 0;
#pragma unroll
    for (int i = 0; i < 8; i++) {
      float a = sc[i][hh] * inv_s[hh] * msk[i] * invn[i];
      packed |= (u64)f2fp8(a * 131072.f) << (8 * i);
      lsv[hh] += a;
    }
    *(u64*)(ap + (long)hh * NV * NE + (long)v * NE + e0) = packed;
  }
#pragma unroll
  for (int hh = 0; hh < 4; hh++) {
    float x = lsv[hh];
#pragma unroll
    for (int m = 1; m <= 32; m <<= 1) x += __shfl_xor(x, m);
    if (lane == 0) redV[hh][wave] = x;
  }
  __syncthreads();
  if (t == 0)
#pragma unroll
    for (int hh = 0; hh < 4; hh++)
      sv[v * 4 + hh] = redV[hh][0] + redV[hh][1] + redV[hh][2] + redV[hh][3];
}

// Fused: sum 8 split-K partials + residual + LayerNorm -> out
__global__ __launch_bounds__(256) void k_redln(
    const float* __restrict__ part, const float* __restrict__ Wh,
    const float* __restrict__ G, const float* __restrict__ sv,
    const float* __restrict__ lng, const float* __restrict__ lnb,
    float* __restrict__ out) {
  int v = blockIdx.x, t = threadIdx.x;
  float x = 0.f;
#pragma unroll
  for (int s = 0; s < 8; s++) x += part[(long)s * NV * 256 + (long)v * 256 + t];
  int z = t >> 6;
  float corr = 1.f - sv[v * 4 + z] * G[(long)v * NV + v];
  x += Wh[(long)v * 256 + t] * corr;
  __shared__ float red[256];
  red[t] = x;
  __syncthreads();
  for (int s = 128; s; s >>= 1) {
    if (t < s) red[t] += red[t + s];
    __syncthreads();
  }
  float mu = red[0] * (1.f / 256.f);
  __syncthreads();
  float d = x - mu;
  red[t] = d * d;
  __syncthreads();
  for (int s = 128; s; s >>= 1) {
    if (t < s) red[t] += red[t + s];
    __syncthreads();
  }
  float var = red[0] * (1.f / 256.f);
  out[(long)v * 256 + t] = d / sqrtf(var + 1e-5f) * lng[t] + lnb[t];
}

extern "C" void kernel_launch(void* const* d_in, const int* in_sizes, int n_in,
                              void* d_out, int out_size, void* d_ws, size_t ws_size,
                              hipStream_t stream) {
  const float* h = (const float*)d_in[0];
  const float* ce = (const float*)d_in[1];
  const float* W = (const float*)d_in[2];
  const float* attn_w = (const float*)d_in[3];
  const float* enc_w = (const float*)d_in[4];
  const float* enc_b = (const float*)d_in[5];
  const float* g1w = (const float*)d_in[6];
  const float* g1b = (const float*)d_in[7];
  const float* g2w = (const float*)d_in[8];
  const float* g2b = (const float*)d_in[9];
  const float* lng = (const float*)d_in[10];
  const float* lnb = (const float*)d_in[11];
  const int* inc = (const int*)d_in[12];
  float* out = (float*)d_out;

  size_t off = 0;
  char* base = (char*)d_ws;
  auto alloc = [&](size_t bytes) {
    void* p = base + off;
    off += (bytes + 255) & ~(size_t)255;
    return p;
  };
  float* Wh = (float*)alloc((size_t)NV * 256 * 4);
  float* cnt = (float*)alloc((size_t)NE * 4);
  float* qv = (float*)alloc((size_t)NV * 4 * 4);
  float* qe = (float*)alloc((size_t)NV * 4 * 4);
  float* se = (float*)alloc((size_t)NE * 4 * 4);
  float* sv = (float*)alloc((size_t)NV * 4 * 4);
  float* G = (float*)alloc((size_t)NV * NV * 4);
  u8* wce = (u8*)alloc((size_t)NV * NV);
  u8* Mbf = (u8*)alloc((size_t)NV * NE);
  u16* Whht = (u16*)alloc((size_t)256 * NV * 2);
  float* Pr = (float*)alloc((size_t)NV * NE * 4);  // P(bf16, first 4MB) / partials
  u8* ap = (u8*)alloc((size_t)4 * NV * NE);
  u16* Bh = (u16*)alloc((size_t)4 * NV * NV * 2);
  // aliases (lifetimes don't overlap):
  u16* P = (u16*)Pr;        // bf16 P (4MB of the 8MB region)
  float* part = Pr;         // cnt/qe partials (640KB), dead before P written
  u8* Mtbf = (u8*)Bh;       // Mtbf (2MB) dead before Bh written (step 7)
  float* part8 = Pr;        // step-8 split-K partials (8MB), P dead after softmax
  (void)ws_size;
  (void)in_sizes;
  (void)n_in;
  (void)out_size;

  // 1. Wh = h @ W (f32) + fused Whht (bf16 transposed) epilogue
  mm_f32<<<dim3(256 / 64, NV / 64), 256, 0, stream>>>(h, W, Wh, Whht);
  // 2. qv, qe
  k_qse1<<<NV, 256, 0, stream>>>(Wh, attn_w, qv, qe);
  // 3. fp8 incidence + fused cnt/qe partial sums (needs qe)
  k_conv<<<dim3(NE / 64, NV / 64), 256, 0, stream>>>(inc, qe, Mbf, Mtbf, part);
  k_sered<<<dim3(NE / 256, 5), 256, 0, stream>>>(part, cnt, se);
  // 4. G, wce(fp8 x512)
  k_G<<<(NV * NV) / 256, 256, 0, stream>>>(ce, enc_w, attn_w, g1w, g1b, g2w, g2b, G, wce);
  // 5. P(bf16) = wce @ M (M=1024, N=2048, K=1024) in fp8; unscale 1/512.
  mfma8_w2<0><<<dim3(NV / 64, NE / 64, 1), 128, 0, stream>>>(
      wce, NV, 0, Mtbf, NV, 0, P, NE, 0, NV, 1.f / 512.f, nullptr);
  // 6. softmax -> ap planes (fp8 x 2^17), s_v. Coalesced, shuffle-reduced.
  k_softmax<<<NV, 256, 0, stream>>>(P, Mbf, cnt, qv, se, ce, enc_w, attn_w, enc_b, ap, sv);
  // 7. Bh = (ap_h @ M^T) * G (4 x M=N=1024, K=2048) in fp8; unscale 2^-17.
  mfma8_w2<1><<<dim3(NV / 64, NV / 64, 4), 128, 0, stream>>>(
      ap, NE, (long)NV * NE, Mbf, NE, 0, Bh, NV, (long)NV * NV, NE, 1.f / 131072.f, G);
  // 8. split-K=8 partials via 4-wave mfma_bt8 (bf16, r7 config).
  mfma_bt8<<<dim3(1, NV / 128, 32), 256, 0, stream>>>(Bh, Whht, part8);
  // 9. reduce partials + residual + LayerNorm
  k_redln<<<NV, 256, 0, stream>>>(part8, Wh, G, sv, lng, lnb, out);
}

// Round 17
// 93.721 us; speedup vs baseline: 1.0754x; 1.0005x over previous
//
#include <hip/hip_runtime.h>
#include <hip/hip_bf16.h>

#define NV 1024
#define NE 2048

typedef unsigned short u16;
typedef unsigned char u8;
typedef unsigned long long u64;
typedef __attribute__((ext_vector_type(8))) short bf16x8;
typedef __attribute__((ext_vector_type(4))) float f32x4;
typedef __attribute__((ext_vector_type(16))) float f32x16;
typedef __attribute__((ext_vector_type(2))) long i64x2;

__device__ __forceinline__ float bf2f(u16 u) { return __uint_as_float(((unsigned)u) << 16); }
__device__ __forceinline__ u16 f2bf(float f) {
  unsigned x = __float_as_uint(f);
  return (u16)((x + 0x7fffu + ((x >> 16) & 1u)) >> 16);
}
// float -> OCP e4m3fn, RNE, saturating, subnormal-continuous.
__device__ __forceinline__ u8 f2fp8(float f) {
  unsigned x = __float_as_uint(f);
  unsigned sgn = (x >> 24) & 0x80;
  float af = __uint_as_float(x & 0x7fffffff);
  unsigned q;
  if (af >= 448.f) {
    q = 0x7e;
  } else if (af < 0.015625f) {        // subnormal range, quantum 2^-9
    q = (unsigned)rintf(af * 512.f);  // 8 == first normal (2^-6): continuous
  } else {
    unsigned xa = x & 0x7fffffff;
    xa += 0x7ffff + ((xa >> 20) & 1);  // RNE into bit 20
    q = (xa >> 20) - 960;              // (exp127<<3 | man3) - (120<<3)
    if (q > 0x7e) q = 0x7e;
  }
  return (u8)(sgn | q);
}

// async global->LDS, 16B per lane, wave-uniform LDS base + lane*16
#define GLL(src, dst)                                                        \
  __builtin_amdgcn_global_load_lds(                                          \
      (const __attribute__((address_space(1))) void*)(src),                  \
      (__attribute__((address_space(3))) void*)(dst), 16, 0, 0)

template <int N>
__device__ __forceinline__ void waitcnt_vm() {
  if constexpr (N == 0) asm volatile("s_waitcnt vmcnt(0)" ::: "memory");
  else if constexpr (N == 3) asm volatile("s_waitcnt vmcnt(3)" ::: "memory");
  else if constexpr (N == 8) asm volatile("s_waitcnt vmcnt(8)" ::: "memory");
}
__device__ __forceinline__ void waitcnt_lgkm0() {
  asm volatile("s_waitcnt lgkmcnt(0)" ::: "memory");
}
__device__ __forceinline__ void barrier_raw() { __builtin_amdgcn_s_barrier(); }

// Swizzled LDS layout: logical byte L lives at physical P = L ^ (((L>>6)&7)<<4)
// (bijective). global_load_lds writes linear physical granules, so the
// per-lane GLOBAL SOURCE is permuted by the inverse map; reads apply fwdswz.
__device__ __forceinline__ void invswz(int g, int& row, int& kq) {
  int pb = g * 16;
  int lb = pb ^ ((((pb >> 8) & 1) << 6) | (((pb >> 7) & 1) << 5) |
                 ((((pb >> 6) ^ (pb >> 8)) & 1) << 4));
  row = lb >> 6;
  kq = lb & 63;
}
__device__ __forceinline__ int fwdswz(int la) { return la ^ (((la >> 6) & 7) << 4); }

// ---------------------------------------------------------------------------
// FP8 2-wave intra-block split-K bt-GEMM (steps 5 & 7): 128 threads, output
// tile 64x64, mfma_f32_32x32x16_fp8_fp8. LDS tile = [64 rows][64 K] fp8 = 4KB.
// Wave w pipelines K-half depth-2, counted vmcnt, no loop barriers.
// T1 XCD-bijective block swizzle (nwg%8==0 at both call sites): each XCD gets
// a CONTIGUOUS chunk of work ids -> per-XCD A working set L2-fits (one head).
// unsc multiplies the accumulator on store. Static acc indices (rule #20).
// EPI 0: bf16 store of acc*unsc (P). EPI 1: bf16 store of acc*unsc*Gm (Bh).
// Requires K/128 even >= 2.
// ---------------------------------------------------------------------------
template <int EPI>
__global__ __launch_bounds__(128) void mfma8_w2(
    const u8* __restrict__ A, int lda, long sA,
    const u8* __restrict__ BT, int ldb, long sBT,
    void* __restrict__ Cp, int ldc, long sC, int K, float unsc,
    const float* __restrict__ Gm) {
  __shared__ __align__(16) char L[32768];
  const int t = threadIdx.x;
  const int wave = t >> 6, lane = t & 63;
  const int l31 = lane & 31, lh = lane >> 5;
  // T1 XCD swizzle: dispatch id -> contiguous work chunk per XCD
  int lid = blockIdx.x + gridDim.x * (blockIdx.y + gridDim.y * blockIdx.z);
  int chunk = (gridDim.x * gridDim.y * gridDim.z) >> 3;
  int swz = (lid & 7) * chunk + (lid >> 3);
  int bx = swz % gridDim.x;
  int tmp = swz / gridDim.x;
  int by = tmp % gridDim.y;
  int bz = tmp / gridDim.y;
  const int m0 = bx * 64, n0 = by * 64;
  const int zz = bz;
  const u8* Ab = A + sA * zz;
  const u8* Bb = BT + sBT * zz;

  char* Lw = L + wave * 16384;
  char* A0 = Lw;
  char* B0 = Lw + 4096;
  char* A1 = Lw + 8192;
  char* B1 = Lw + 12288;

  int rL[4], qL[4];
#pragma unroll
  for (int j = 0; j < 4; j++) invswz(j * 64 + lane, rL[j], qL[j]);

  f32x16 acc[2][2] = {};

  auto stage = [&](char* Ad, char* Bd, int tile) {
    waitcnt_lgkm0();
    const long kb = (long)tile * 64;
#pragma unroll
    for (int j = 0; j < 4; j++)
      GLL(Ab + (long)(m0 + rL[j]) * lda + kb + qL[j], Ad + j * 1024);
#pragma unroll
    for (int j = 0; j < 4; j++)
      GLL(Bb + (long)(n0 + rL[j]) * ldb + kb + qL[j], Bd + j * 1024);
  };
  auto comp = [&](const char* A_, const char* B_) {
#pragma unroll
    for (int kss2 = 0; kss2 < 2; kss2++) {
      i64x2 av[2], bv[2];
#pragma unroll
      for (int mi = 0; mi < 2; mi++)
        av[mi] = *(const i64x2*)(A_ + fwdswz((mi * 32 + l31) * 64 + kss2 * 32 + lh * 16));
#pragma unroll
      for (int ni = 0; ni < 2; ni++)
        bv[ni] = *(const i64x2*)(B_ + fwdswz((ni * 32 + l31) * 64 + kss2 * 32 + lh * 16));
#pragma unroll
      for (int mi = 0; mi < 2; mi++)
#pragma unroll
        for (int ni = 0; ni < 2; ni++) {
          acc[mi][ni] = __builtin_amdgcn_mfma_f32_32x32x16_fp8_fp8(
              av[mi][0], bv[ni][0], acc[mi][ni], 0, 0, 0);
          acc[mi][ni] = __builtin_amdgcn_mfma_f32_32x32x16_fp8_fp8(
              av[mi][1], bv[ni][1], acc[mi][ni], 0, 0, 0);
        }
    }
  };

  const int nt2 = K / 128;
  const int tb = wave * nt2;
  stage(A0, B0, tb);
  for (int i = 0; i + 2 < nt2; i += 2) {
    stage(A1, B1, tb + i + 1);
    waitcnt_vm<8>();
    comp(A0, B0);
    stage(A0, B0, tb + i + 2);
    waitcnt_vm<8>();
    comp(A1, B1);
  }
  stage(A1, B1, tb + nt2 - 1);
  waitcnt_vm<8>();
  comp(A0, B0);
  waitcnt_vm<0>();
  comp(A1, B1);

  waitcnt_lgkm0();
  float4* myD = (float4*)Lw;
  const float* otD = (const float*)(L + (wave ^ 1) * 16384);
  if (wave == 0) {
#pragma unroll
    for (int ni = 0; ni < 2; ni++)
#pragma unroll
      for (int r4 = 0; r4 < 4; r4++)
        myD[r4 * 128 + ni * 64 + lane] =
            make_float4(acc[1][ni][r4 * 4 + 0], acc[1][ni][r4 * 4 + 1],
                        acc[1][ni][r4 * 4 + 2], acc[1][ni][r4 * 4 + 3]);
  } else {
#pragma unroll
    for (int ni = 0; ni < 2; ni++)
#pragma unroll
      for (int r4 = 0; r4 < 4; r4++)
        myD[r4 * 128 + ni * 64 + lane] =
            make_float4(acc[0][ni][r4 * 4 + 0], acc[0][ni][r4 * 4 + 1],
                        acc[0][ni][r4 * 4 + 2], acc[0][ni][r4 * 4 + 3]);
  }
  __syncthreads();

  auto store_one = [&](int m, int n, float vv) {
    if constexpr (EPI == 0) {
      ((u16*)Cp)[sC * zz + (long)m * ldc + n] = f2bf(vv * unsc);
    } else {
      ((u16*)Cp)[sC * zz + (long)m * ldc + n] = f2bf(vv * unsc * Gm[(long)m * NV + n]);
    }
  };
  if (wave == 0) {
#pragma unroll
    for (int ni = 0; ni < 2; ni++)
#pragma unroll
      for (int r = 0; r < 16; r++) {
        float vv = acc[0][ni][r] + otD[((r >> 2) * 128 + ni * 64 + lane) * 4 + (r & 3)];
        int m = m0 + (r & 3) + 8 * (r >> 2) + 4 * lh;
        store_one(m, n0 + ni * 32 + l31, vv);
      }
  } else {
#pragma unroll
    for (int ni = 0; ni < 2; ni++)
#pragma unroll
      for (int r = 0; r < 16; r++) {
        float vv = acc[1][ni][r] + otD[((r >> 2) * 128 + ni * 64 + lane) * 4 + (r & 3)];
        int m = m0 + 32 + (r & 3) + 8 * (r >> 2) + 4 * lh;
        store_one(m, n0 + ni * 32 + l31, vv);
      }
  }
}

// ---------------------------------------------------------------------------
// 16x16-frag 4-wave bt-GEMM for step 8 split-K (r7 config, bf16).
// ---------------------------------------------------------------------------
__global__ __launch_bounds__(256) void mfma_bt8(
    const u16* __restrict__ A, const u16* __restrict__ BT,
    float* __restrict__ Cp) {
  constexpr int FM = 4, FN = 2;
  __shared__ __align__(16) char As0[8192];
  __shared__ __align__(16) char As1[8192];
  __shared__ __align__(16) char Bs0[4096];
  __shared__ __align__(16) char Bs1[4096];
  const int t = threadIdx.x;
  const int wave = t >> 6, lane = t & 63;
  const int lhi = lane >> 4, llo = lane & 15;
  const int wm = (wave >> 1) * 64, wn = (wave & 1) * 32;
  const int m0 = blockIdx.y * 128;
  const int zz = blockIdx.z >> 3, ks = blockIdx.z & 7;
  const char* Ab = (const char*)(A + (long)NV * NV * zz + ks * 128);
  const char* Bb = (const char*)(BT + (long)64 * NV * zz + ks * 128);
  const long lda2 = (long)NV * 2, ldb2 = (long)NV * 2;

  int rA0, qA0, rA1, qA1;
  invswz(t, rA0, qA0);
  invswz(t + 256, rA1, qA1);
  const int wofs = (t & 192) * 16;

  f32x4 acc[FM][FN] = {};

  auto stage = [&](char* Ad, char* Bd, int k0) {
    const long kb = (long)k0 * 2;
    GLL(Ab + (long)(m0 + rA0) * lda2 + kb + qA0, Ad + wofs);
    GLL(Ab + (long)(m0 + rA1) * lda2 + kb + qA1, Ad + 4096 + wofs);
    GLL(Bb + (long)rA0 * ldb2 + kb + qA0, Bd + wofs);
  };
  auto compute = [&](const char* A_, const char* B_) {
    bf16x8 af[FM], bfv[FN];
#pragma unroll
    for (int mi = 0; mi < FM; mi++)
      af[mi] = *(const bf16x8*)(A_ + fwdswz((wm + mi * 16 + llo) * 64 + lhi * 16));
#pragma unroll
    for (int ni = 0; ni < FN; ni++)
      bfv[ni] = *(const bf16x8*)(B_ + fwdswz((wn + ni * 16 + llo) * 64 + lhi * 16));
#pragma unroll
    for (int mi = 0; mi < FM; mi++)
#pragma unroll
      for (int ni = 0; ni < FN; ni++)
        acc[mi][ni] =
            __builtin_amdgcn_mfma_f32_16x16x32_bf16(af[mi], bfv[ni], acc[mi][ni], 0, 0, 0);
  };

  stage(As0, Bs0, 0);
  stage(As1, Bs1, 32);
  waitcnt_vm<3>();
  barrier_raw();
  compute(As0, Bs0);
  barrier_raw();
  stage(As0, Bs0, 64);
  waitcnt_vm<3>();
  barrier_raw();
  compute(As1, Bs1);
  barrier_raw();
  stage(As1, Bs1, 96);
  waitcnt_vm<3>();
  barrier_raw();
  compute(As0, Bs0);
  waitcnt_vm<0>();
  barrier_raw();
  compute(As1, Bs1);

#pragma unroll
  for (int mi = 0; mi < FM; mi++)
#pragma unroll
    for (int ni = 0; ni < FN; ni++)
#pragma unroll
      for (int r = 0; r < 4; r++) {
        int m = m0 + wm + mi * 16 + lhi * 4 + r;
        int n = wn + ni * 16 + llo;
        Cp[(long)ks * (NV * 256) + (long)m * 256 + zz * 64 + n] = acc[mi][ni][r];
      }
}

// ---------------------------------------------------------------------------
// Step 1: Wh = h @ W, 32x64 tile (128 blocks, 2x the CU coverage of the old
// 64x64 grid), BK=16, micro 2x4 + FUSED transposed-bf16 Whht epilogue.
// ---------------------------------------------------------------------------
__global__ __launch_bounds__(256) void mm_f32(
    const float* __restrict__ Ap, const float* __restrict__ Bp,
    float* __restrict__ Cp, u16* __restrict__ Whht) {
  __shared__ float As[16][36];
  __shared__ float Bs[16][68];
  __shared__ u16 ttile[64][36];
  const int t = threadIdx.x;
  const int tx = t & 15, ty = t >> 4;
  const int m0 = blockIdx.y * 32, n0 = blockIdx.x * 64;
  float acc[2][4] = {};
  for (int k0 = 0; k0 < 256; k0 += 16) {
    if (t < 128) {
      int row = t >> 2, k4 = (t & 3) * 4;
      float4 a4 = *(const float4*)(Ap + (long)(m0 + row) * 256 + k0 + k4);
      As[k4 + 0][row] = a4.x;
      As[k4 + 1][row] = a4.y;
      As[k4 + 2][row] = a4.z;
      As[k4 + 3][row] = a4.w;
    }
    {
      int bk = t >> 4, bn = (t & 15) * 4;
      float4 b4 = *(const float4*)(Bp + (long)(k0 + bk) * 256 + n0 + bn);
      Bs[bk][bn + 0] = b4.x;
      Bs[bk][bn + 1] = b4.y;
      Bs[bk][bn + 2] = b4.z;
      Bs[bk][bn + 3] = b4.w;
    }
    __syncthreads();
#pragma unroll
    for (int kk = 0; kk < 16; kk++) {
      float a[2], b[4];
      a[0] = As[kk][ty * 2 + 0];
      a[1] = As[kk][ty * 2 + 1];
      *(float4*)b = *(const float4*)&Bs[kk][tx * 4];
#pragma unroll
      for (int i = 0; i < 2; i++)
#pragma unroll
        for (int j = 0; j < 4; j++) acc[i][j] = fmaf(a[i], b[j], acc[i][j]);
    }
    __syncthreads();
  }
#pragma unroll
  for (int i = 0; i < 2; i++)
#pragma unroll
    for (int j = 0; j < 4; j++) {
      Cp[(long)(m0 + ty * 2 + i) * 256 + n0 + tx * 4 + j] = acc[i][j];
      ttile[tx * 4 + j][ty * 2 + i] = f2bf(acc[i][j]);  // [c_local][v_local]
    }
  __syncthreads();
  // coalesced transposed store: 4 threads per c-row, 8 u16 each
  const int cr = t >> 2, vc = (t & 3) * 8;
#pragma unroll
  for (int q = 0; q < 2; q++) {
    ushort4 w = *(const ushort4*)&ttile[cr][vc + q * 4];
    *(ushort4*)&Whht[(long)(n0 + cr) * NV + m0 + vc + q * 4] = w;
  }
}

// Build Mbf/Mtbf (fp8: 1.0 = 0x38) AND fused per-(e, v-tile) partial cnt/qe
// sums. part[(j*16+b)*NE + e], j=0 cnt, j=1..4 qe-sums.
__global__ __launch_bounds__(256) void k_conv(const int* __restrict__ inc,
                                              const float* __restrict__ qe,
                                              u8* __restrict__ Mbf,
                                              u8* __restrict__ Mtbf,
                                              float* __restrict__ part) {
  __shared__ u8 tile[64][68];
  const int e0 = blockIdx.x * 64, v0 = blockIdx.y * 64;
  const int t = threadIdx.x;
#pragma unroll
  for (int p = 0; p < 4; p++) {
    int r = p * 16 + (t >> 4);
    int c4 = (t & 15) * 4;
    int4 q = *(const int4*)(inc + (long)(v0 + r) * NE + e0 + c4);
    uchar4 w;
    w.x = q.x > 0 ? 0x38 : 0;
    w.y = q.y > 0 ? 0x38 : 0;
    w.z = q.z > 0 ? 0x38 : 0;
    w.w = q.w > 0 ? 0x38 : 0;
    *(uchar4*)&Mbf[(long)(v0 + r) * NE + e0 + c4] = w;
    tile[c4 + 0][r] = w.x;
    tile[c4 + 1][r] = w.y;
    tile[c4 + 2][r] = w.z;
    tile[c4 + 3][r] = w.w;
  }
  __syncthreads();
#pragma unroll
  for (int p = 0; p < 4; p++) {
    int er = p * 16 + (t >> 4);
    int vc4 = (t & 15) * 4;
    uchar4 w;
    w.x = tile[er][vc4 + 0];
    w.y = tile[er][vc4 + 1];
    w.z = tile[er][vc4 + 2];
    w.w = tile[er][vc4 + 3];
    *(uchar4*)&Mtbf[(long)(e0 + er) * NV + v0 + vc4] = w;
  }
  int er = t >> 2, q4 = t & 3;
  float c = 0, s0 = 0, s1 = 0, s2 = 0, s3 = 0;
  for (int vl = q4 * 16; vl < q4 * 16 + 16; vl++) {
    if (tile[er][vl]) {
      c += 1.f;
      const float* q4p = &qe[(long)(v0 + vl) * 4];
      s0 += q4p[0];
      s1 += q4p[1];
      s2 += q4p[2];
      s3 += q4p[3];
    }
  }
#pragma unroll
  for (int m = 1; m <= 2; m <<= 1) {
    c += __shfl_xor(c, m);
    s0 += __shfl_xor(s0, m);
    s1 += __shfl_xor(s1, m);
    s2 += __shfl_xor(s2, m);
    s3 += __shfl_xor(s3, m);
  }
  if (q4 == 0) {
    int b = blockIdx.y;
    int e = e0 + er;
    part[(0 * 16 + b) * NE + e] = c;
    part[(1 * 16 + b) * NE + e] = s0;
    part[(2 * 16 + b) * NE + e] = s1;
    part[(3 * 16 + b) * NE + e] = s2;
    part[(4 * 16 + b) * NE + e] = s3;
  }
}

// qv[v,h] = Whh[v,h,:].a_v ; qe[v,h] = Whh[v,h,:].a_e
__global__ __launch_bounds__(256) void k_qse1(const float* __restrict__ Wh,
                                              const float* __restrict__ attn_w,
                                              float* __restrict__ qv, float* __restrict__ qe) {
  int v = blockIdx.x, t = threadIdx.x;
  int d = t & 63, h = t >> 6;
  float x = Wh[(long)v * 256 + t];
  float pv = x * attn_w[d];
  float pe = x * attn_w[64 + d];
  for (int s = 32; s; s >>= 1) {
    pv += __shfl_down(pv, s);
    pe += __shfl_down(pe, s);
  }
  if (d == 0) {
    qv[v * 4 + h] = pv;
    qe[v * 4 + h] = pe;
  }
}

// Deterministic reduction of the 16 slabs. se holds RAW sums.
__global__ __launch_bounds__(256) void k_sered(const float* __restrict__ part,
                                               float* __restrict__ cnt, float* __restrict__ se) {
  int e = blockIdx.x * 256 + threadIdx.x;
  int j = blockIdx.y;
  float s = 0;
  for (int b = 0; b < 16; b++) s += part[(j * 16 + b) * NE + e];
  if (j == 0)
    cnt[e] = s;
  else
    se[e * 4 + (j - 1)] = s;
}

// Per (v,u): gate G via 2->32->1 MLP, and wce (fp8, x512) = ce.(enc_w @ a_c)
__global__ __launch_bounds__(256) void k_G(const float* __restrict__ ce,
                                           const float* __restrict__ enc_w,
                                           const float* __restrict__ attn_w,
                                           const float* __restrict__ g1w,
                                           const float* __restrict__ g1b,
                                           const float* __restrict__ g2w,
                                           const float* __restrict__ g2b,
                                           float* __restrict__ G, u8* __restrict__ wce) {
  long idx = (long)blockIdx.x * 256 + threadIdx.x;
  float2 c = *(const float2*)(ce + idx * 2);
  float ew0 = 0, ew1 = 0;
#pragma unroll
  for (int j = 0; j < 8; j++) {
    float ac = attn_w[128 + j];
    ew0 += enc_w[j] * ac;
    ew1 += enc_w[8 + j] * ac;
  }
  wce[idx] = f2fp8((c.x * ew0 + c.y * ew1) * 512.f);
  float s = g2b[0];
#pragma unroll
  for (int j = 0; j < 32; j++) {
    float zz = fmaxf(c.x * g1w[j] + c.y * g1w[32 + j] + g1b[j], 0.f);
    s = fmaf(zz, g2w[j], s);
  }
  G[idx] = 1.f / (1.f + __expf(-s));
}

// Per v: scores -> leaky_relu -> mask -> softmax over E -> ap (fp8 planes,
// scaled x 2^17), s_v. Thread t owns e in [t*8, t*8+8): coalesced u64/float4
// loads, u64 ap stores. Reductions: wave __shfl_xor + 4-slot LDS (3 barriers).
__global__ __launch_bounds__(256) void k_softmax(
    const u16* __restrict__ P, const u8* __restrict__ Mbf, const float* __restrict__ cnt,
    const float* __restrict__ qv, const float* __restrict__ se, const float* __restrict__ ce,
    const float* __restrict__ enc_w, const float* __restrict__ attn_w,
    const float* __restrict__ enc_b, u8* __restrict__ ap, float* __restrict__ sv) {
  int v = blockIdx.x, t = threadIdx.x;
  const int wave = t >> 6, lane = t & 63;
  float ew0 = 0, ew1 = 0, ebac = 0;
#pragma unroll
  for (int j = 0; j < 8; j++) {
    float ac = attn_w[128 + j];
    ew0 += enc_w[j] * ac;
    ew1 += enc_w[8 + j] * ac;
    ebac += enc_b[j] * ac;
  }
  float dce = ce[((long)v * NV + v) * 2] * ew0 + ce[((long)v * NV + v) * 2 + 1] * ew1;
  float svh[4];
#pragma unroll
  for (int hh = 0; hh < 4; hh++) svh[hh] = qv[v * 4 + hh];

  const int e0 = t * 8;
  u64 mb = *(const u64*)(Mbf + (long)v * NE + e0);
  ushort4 pb0 = *(const ushort4*)(P + (long)v * NE + e0);
  ushort4 pb1 = *(const ushort4*)(P + (long)v * NE + e0 + 4);
  float pv8[8], cn8[8];
  pv8[0] = bf2f(pb0.x); pv8[1] = bf2f(pb0.y); pv8[2] = bf2f(pb0.z); pv8[3] = bf2f(pb0.w);
  pv8[4] = bf2f(pb1.x); pv8[5] = bf2f(pb1.y); pv8[6] = bf2f(pb1.z); pv8[7] = bf2f(pb1.w);
  *(float4*)&cn8[0] = *(const float4*)(cnt + e0);
  *(float4*)&cn8[4] = *(const float4*)(cnt + e0 + 4);
  float se8[8][4];
#pragma unroll
  for (int i = 0; i < 8; i++) *(float4*)&se8[i][0] = *(const float4*)(se + (long)(e0 + i) * 4);

  float sc[8][4];
  float invn[8], msk[8];
  float mx[4] = {-3e38f, -3e38f, -3e38f, -3e38f};
#pragma unroll
  for (int i = 0; i < 8; i++) {
    float cnte = cn8[i];
    float mask = ((mb >> (8 * i)) & 0xff) ? 1.f : 0.f;
    float nve = cnte - mask;
    float inv = nve > 0.f ? 1.f / nve : 0.f;
    float rdg = 1.f / fmaxf(cnte, 1.f);
    invn[i] = inv;
    msk[i] = mask;
    float cc = inv * (pv8[i] - mask * dce) + ebac;
#pragma unroll
    for (int hh = 0; hh < 4; hh++) {
      float s = svh[hh] + se8[i][hh] * rdg + cc;
      s = s > 0.f ? s : 0.2f * s;
      s = mask > 0.f ? s : -1e9f;
      sc[i][hh] = s;
      mx[hh] = fmaxf(mx[hh], s);
    }
  }
  __shared__ float redM[4][4], redS[4][4], redV[4][4];  // [hh][wave]
#pragma unroll
  for (int hh = 0; hh < 4; hh++) {
    float x = mx[hh];
#pragma unroll
    for (int m = 1; m <= 32; m <<= 1) x = fmaxf(x, __shfl_xor(x, m));
    if (lane == 0) redM[hh][wave] = x;
  }
  __syncthreads();
  float gm[4];
#pragma unroll
  for (int hh = 0; hh < 4; hh++)
    gm[hh] = fmaxf(fmaxf(redM[hh][0], redM[hh][1]), fmaxf(redM[hh][2], redM[hh][3]));

  float lsum[4] = {0, 0, 0, 0};
#pragma unroll
  for (int i = 0; i < 8; i++)
#pragma unroll
    for (int hh = 0; hh < 4; hh++) {
      float p = __expf(sc[i][hh] - gm[hh]);
      sc[i][hh] = p;
      lsum[hh] += p;
    }
#pragma unroll
  for (int hh = 0; hh < 4; hh++) {
    float x = lsum[hh];
#pragma unroll
    for (int m = 1; m <= 32; m <<= 1) x += __shfl_xor(x, m);
    if (lane == 0) redS[hh][wave] = x;
  }
  __syncthreads();
  float inv_s[4];
#pragma unroll
  for (int hh = 0; hh < 4; hh++)
    inv_s[hh] = 1.f / (redS[hh][0] + redS[hh][1] + redS[hh][2] + redS[hh][3]);

  float lsv[4] = {0, 0, 0, 0};
#pragma unroll
  for (int hh = 0; hh < 4; hh++) {
    u64 packed = 0;
#pragma unroll
    for (int i = 0; i < 8; i++) {
      float a = sc[i][hh] * inv_s[hh] * msk[i] * invn[i];
      packed |= (u64)f2fp8(a * 131072.f) << (8 * i);
      lsv[hh] += a;
    }
    *(u64*)(ap + (long)hh * NV * NE + (long)v * NE + e0) = packed;
  }
#pragma unroll
  for (int hh = 0; hh < 4; hh++) {
    float x = lsv[hh];
#pragma unroll
    for (int m = 1; m <= 32; m <<= 1) x += __shfl_xor(x, m);
    if (lane == 0) redV[hh][wave] = x;
  }
  __syncthreads();
  if (t == 0)
#pragma unroll
    for (int hh = 0; hh < 4; hh++)
      sv[v * 4 + hh] = redV[hh][0] + redV[hh][1] + redV[hh][2] + redV[hh][3];
}

// Fused: sum 8 split-K partials + residual + LayerNorm -> out
__global__ __launch_bounds__(256) void k_redln(
    const float* __restrict__ part, const float* __restrict__ Wh,
    const float* __restrict__ G, const float* __restrict__ sv,
    const float* __restrict__ lng, const float* __restrict__ lnb,
    float* __restrict__ out) {
  int v = blockIdx.x, t = threadIdx.x;
  float x = 0.f;
#pragma unroll
  for (int s = 0; s < 8; s++) x += part[(long)s * NV * 256 + (long)v * 256 + t];
  int z = t >> 6;
  float corr = 1.f - sv[v * 4 + z] * G[(long)v * NV + v];
  x += Wh[(long)v * 256 + t] * corr;
  __shared__ float red[256];
  red[t] = x;
  __syncthreads();
  for (int s = 128; s; s >>= 1) {
    if (t < s) red[t] += red[t + s];
    __syncthreads();
  }
  float mu = red[0] * (1.f / 256.f);
  __syncthreads();
  float d = x - mu;
  red[t] = d * d;
  __syncthreads();
  for (int s = 128; s; s >>= 1) {
    if (t < s) red[t] += red[t + s];
    __syncthreads();
  }
  float var = red[0] * (1.f / 256.f);
  out[(long)v * 256 + t] = d / sqrtf(var + 1e-5f) * lng[t] + lnb[t];
}

extern "C" void kernel_launch(void* const* d_in, const int* in_sizes, int n_in,
                              void* d_out, int out_size, void* d_ws, size_t ws_size,
                              hipStream_t stream) {
  const float* h = (const float*)d_in[0];
  const float* ce = (const float*)d_in[1];
  const float* W = (const float*)d_in[2];
  const float* attn_w = (const float*)d_in[3];
  const float* enc_w = (const float*)d_in[4];
  const float* enc_b = (const float*)d_in[5];
  const float* g1w = (const float*)d_in[6];
  const float* g1b = (const float*)d_in[7];
  const float* g2w = (const float*)d_in[8];
  const float* g2b = (const float*)d_in[9];
  const float* lng = (const float*)d_in[10];
  const float* lnb = (const float*)d_in[11];
  const int* inc = (const int*)d_in[12];
  float* out = (float*)d_out;

  size_t off = 0;
  char* base = (char*)d_ws;
  auto alloc = [&](size_t bytes) {
    void* p = base + off;
    off += (bytes + 255) & ~(size_t)255;
    return p;
  };
  float* Wh = (float*)alloc((size_t)NV * 256 * 4);
  float* cnt = (float*)alloc((size_t)NE * 4);
  float* qv = (float*)alloc((size_t)NV * 4 * 4);
  float* qe = (float*)alloc((size_t)NV * 4 * 4);
  float* se = (float*)alloc((size_t)NE * 4 * 4);
  float* sv = (float*)alloc((size_t)NV * 4 * 4);
  float* G = (float*)alloc((size_t)NV * NV * 4);
  u8* wce = (u8*)alloc((size_t)NV * NV);
  u8* Mbf = (u8*)alloc((size_t)NV * NE);
  u16* Whht = (u16*)alloc((size_t)256 * NV * 2);
  float* Pr = (float*)alloc((size_t)NV * NE * 4);  // P(bf16, first 4MB) / partials
  u8* ap = (u8*)alloc((size_t)4 * NV * NE);
  u16* Bh = (u16*)alloc((size_t)4 * NV * NV * 2);
  // aliases (lifetimes don't overlap):
  u16* P = (u16*)Pr;        // bf16 P (4MB of the 8MB region)
  float* part = Pr;         // cnt/qe partials (640KB), dead before P written
  u8* Mtbf = (u8*)Bh;       // Mtbf (2MB) dead before Bh written (step 7)
  float* part8 = Pr;        // step-8 split-K partials (8MB), P dead after softmax
  (void)ws_size;
  (void)in_sizes;
  (void)n_in;
  (void)out_size;

  // 1. Wh = h @ W (f32, 32x64 tiles -> 128 blocks) + fused Whht epilogue
  mm_f32<<<dim3(256 / 64, NV / 32), 256, 0, stream>>>(h, W, Wh, Whht);
  // 2. qv, qe
  k_qse1<<<NV, 256, 0, stream>>>(Wh, attn_w, qv, qe);
  // 3. fp8 incidence + fused cnt/qe partial sums (needs qe)
  k_conv<<<dim3(NE / 64, NV / 64), 256, 0, stream>>>(inc, qe, Mbf, Mtbf, part);
  k_sered<<<dim3(NE / 256, 5), 256, 0, stream>>>(part, cnt, se);
  // 4. G, wce(fp8 x512)
  k_G<<<(NV * NV) / 256, 256, 0, stream>>>(ce, enc_w, attn_w, g1w, g1b, g2w, g2b, G, wce);
  // 5. P(bf16) = wce @ M (M=1024, N=2048, K=1024) in fp8; unscale 1/512.
  mfma8_w2<0><<<dim3(NV / 64, NE / 64, 1), 128, 0, stream>>>(
      wce, NV, 0, Mtbf, NV, 0, P, NE, 0, NV, 1.f / 512.f, nullptr);
  // 6. softmax -> ap planes (fp8 x 2^17), s_v. Coalesced, shuffle-reduced.
  k_softmax<<<NV, 256, 0, stream>>>(P, Mbf, cnt, qv, se, ce, enc_w, attn_w, enc_b, ap, sv);
  // 7. Bh = (ap_h @ M^T) * G (4 x M=N=1024, K=2048) in fp8; unscale 2^-17.
  mfma8_w2<1><<<dim3(NV / 64, NV / 64, 4), 128, 0, stream>>>(
      ap, NE, (long)NV * NE, Mbf, NE, 0, Bh, NV, (long)NV * NV, NE, 1.f / 131072.f, G);
  // 8. split-K=8 partials via 4-wave mfma_bt8 (bf16, r7 config).
  mfma_bt8<<<dim3(1, NV / 128, 32), 256, 0, stream>>>(Bh, Whht, part8);
  // 9. reduce partials + residual + LayerNorm
  k_redln<<<NV, 256, 0, stream>>>(part8, Wh, G, sv, lng, lnb, out);
}